// Round 1
// baseline (326.731 us; speedup 1.0000x reference)
//
#include <hip/hip_runtime.h>
#include <math.h>

#define MM 65536   // nodes
#define NN 65536   // edges
#define BBATCH 64
#define EPB 1024   // edges per batch row
#define DD 128
#define KTOP 64

// ---------------------------------------------------------------------------
// Kernel 1: G = Wq^T @ Wk   (512x512), G[m][n] = sum_d Wq[d][m]*Wk[d][n]
// 256 blocks of 32x32 tiles, 256 threads (16x16, each 2x2 outputs)
// ---------------------------------------------------------------------------
__global__ void k_gemm_G(const float* __restrict__ Wq, const float* __restrict__ Wk,
                         float* __restrict__ G)
{
    __shared__ float As[32][33];
    __shared__ float Bs[32][33];
    const int t  = threadIdx.x;
    const int tm = t >> 4, tn = t & 15;
    const int m0 = (blockIdx.x >> 4) * 32, n0 = (blockIdx.x & 15) * 32;
    float a00 = 0.f, a01 = 0.f, a10 = 0.f, a11 = 0.f;
    for (int d0 = 0; d0 < 512; d0 += 32) {
        for (int i = t; i < 1024; i += 256) {
            int r = i >> 5, c = i & 31;
            As[r][c] = Wq[(size_t)(d0 + r) * 512 + m0 + c];
            Bs[r][c] = Wk[(size_t)(d0 + r) * 512 + n0 + c];
        }
        __syncthreads();
        #pragma unroll 8
        for (int k = 0; k < 32; ++k) {
            float x0 = As[k][tm * 2], x1 = As[k][tm * 2 + 1];
            float y0 = Bs[k][tn * 2], y1 = Bs[k][tn * 2 + 1];
            a00 += x0 * y0; a01 += x0 * y1; a10 += x1 * y0; a11 += x1 * y1;
        }
        __syncthreads();
    }
    G[(size_t)(m0 + tm * 2 + 0) * 512 + n0 + tn * 2 + 0] = a00;
    G[(size_t)(m0 + tm * 2 + 0) * 512 + n0 + tn * 2 + 1] = a01;
    G[(size_t)(m0 + tm * 2 + 1) * 512 + n0 + tn * 2 + 0] = a10;
    G[(size_t)(m0 + tm * 2 + 1) * 512 + n0 + tn * 2 + 1] = a11;
}

// ---------------------------------------------------------------------------
// Kernel 2: per-batch vectors.
//  qcat = [qs[e]; qr[e]] (256)
//  w[k]   = sum_r G[k][256+r]*qcat[r]   k in [0,512)
//  bL[e]  = w[0:256]
//  bR[e][c] = sum_r qcat[r]*G[256+r][c] c in [0,256)
//  cB[e]  = sum_r qcat[r]*w[256+r]
// 64 blocks x 256 threads
// ---------------------------------------------------------------------------
__global__ void k_batch(const float* __restrict__ qs, const float* __restrict__ qr,
                        const float* __restrict__ G,
                        float* __restrict__ bL, float* __restrict__ bR, float* __restrict__ cB)
{
    const int e = blockIdx.x, t = threadIdx.x;
    __shared__ float qcat[256];
    __shared__ float whi[256];
    __shared__ float red[256];
    qcat[t] = (t < 128) ? qs[(size_t)e * 128 + t] : qr[(size_t)e * 128 + (t - 128)];
    __syncthreads();
    float w0 = 0.f, w1 = 0.f;
    for (int r = 0; r < 256; ++r) {
        float q = qcat[r];
        w0 += G[(size_t)t * 512 + 256 + r] * q;
        w1 += G[(size_t)(t + 256) * 512 + 256 + r] * q;
    }
    bL[(size_t)e * 256 + t] = w0;
    whi[t] = w1;
    float v = 0.f;
    for (int r = 0; r < 256; ++r)
        v += qcat[r] * G[(size_t)(256 + r) * 512 + t];
    bR[(size_t)e * 256 + t] = v;
    __syncthreads();
    red[t] = qcat[t] * whi[t];
    __syncthreads();
    for (int s = 128; s > 0; s >>= 1) {
        if (t < s) red[t] += red[t + s];
        __syncthreads();
    }
    if (t == 0) cB[e] = red[0];
}

// ---------------------------------------------------------------------------
// Kernel 3: per-edge logits.
//  logit[n] = Lh^T Ghh Rh + Lh.bL[eg] + Rh.bR[eg] + cB[eg]
//  Lh = [vnr[seg]; rel[n]], Rh = [vnr[j]; rel[n]], Ghh = G[0:256,0:256]
// 1024 blocks x 256 threads, 64 edges/block (all share the same eg).
// Thread (p = t>>3, g = t&7): edges 2p,2p+1, cols g*8..g*8+7 of each 64-col tile.
// ---------------------------------------------------------------------------
__launch_bounds__(256, 2)
__global__ void k_edge(const float* __restrict__ vnr, const float* __restrict__ rel,
                       const int* __restrict__ edges, const float* __restrict__ G,
                       const float* __restrict__ bL, const float* __restrict__ bR,
                       const float* __restrict__ cB, float* __restrict__ logits)
{
    __shared__ float At[128][64];   // A transposed: At[k][edge]
    __shared__ float Bt[128][64];   // G tile, XOR-swizzled columns
    __shared__ int   segL[64], jL[64];
    __shared__ float bLs[256], bRs[256];

    const int t  = threadIdx.x;
    const int n0 = blockIdx.x * 64;
    const int eg = n0 >> 10;

    if (t < 64) {
        segL[t] = edges[(size_t)(n0 + t) * 8 + 6];
        jL[t]   = edges[(size_t)(n0 + t) * 8 + 7];
    }
    bLs[t] = bL[(size_t)eg * 256 + t];
    bRs[t] = bR[(size_t)eg * 256 + t];

    const int g = t & 7, p = t >> 3;
    const int e0 = 2 * p, e1 = 2 * p + 1;
    const int eS = t & 63, rep = t >> 6;

    double s0 = 0.0, s1 = 0.0;

    for (int kt = 0; kt < 2; ++kt) {
        __syncthreads();   // previous tile fully consumed; segL/jL/bLs visible
        // ---- stage At[k][e]: kt==0 -> vnr[segL[e]][k] (gathered), kt==1 -> rel[n0+e][k]
        {
            const float* src = (kt == 0) ? (vnr + (size_t)segL[eS] * 128)
                                         : (rel + (size_t)(n0 + eS) * 128);
            #pragma unroll
            for (int w = 0; w < 8; ++w) {
                int k = rep * 32 + w * 4;
                float4 v = *(const float4*)(src + k);
                At[k + 0][eS] = v.x; At[k + 1][eS] = v.y;
                At[k + 2][eS] = v.z; At[k + 3][eS] = v.w;
            }
        }
        __syncthreads();
        // ---- bL partial: this thread covers k = g*16 .. g*16+15
        {
            float a0 = 0.f, a1 = 0.f;
            #pragma unroll
            for (int kk = 0; kk < 16; ++kk) {
                int k = g * 16 + kk;
                float bl = bLs[kt * 128 + k];
                a0 += At[k][e0] * bl;
                a1 += At[k][e1] * bl;
            }
            s0 += (double)a0; s1 += (double)a1;
        }
        for (int ct = 0; ct < 4; ++ct) {
            __syncthreads();   // previous Bt fully consumed
            // ---- stage Bt[kk][c^swz] = G[kt*128+kk][ct*64+c]
            {
                int kk = t >> 1, half = t & 1;
                const float* gsrc = G + (size_t)(kt * 128 + kk) * 512 + ct * 64 + half * 32;
                #pragma unroll
                for (int w = 0; w < 8; ++w) {
                    int c  = half * 32 + w * 4;
                    int cs = c ^ ((kk & 7) << 3);
                    *(float4*)&Bt[kk][cs] = *(const float4*)(gsrc + w * 4);
                }
            }
            __syncthreads();
            // ---- 64x64x128 tile: Y[e][c] += A[e][k]*G[k][c]
            float acc0[8] = {0.f,0.f,0.f,0.f,0.f,0.f,0.f,0.f};
            float acc1[8] = {0.f,0.f,0.f,0.f,0.f,0.f,0.f,0.f};
            #pragma unroll 4
            for (int kk = 0; kk < 128; ++kk) {
                const float2 a = *(const float2*)&At[kk][e0];
                const int cb = (g * 8) ^ ((kk & 7) << 3);
                const float4 b0 = *(const float4*)&Bt[kk][cb];
                const float4 b1 = *(const float4*)&Bt[kk][cb + 4];
                acc0[0] += a.x * b0.x; acc0[1] += a.x * b0.y;
                acc0[2] += a.x * b0.z; acc0[3] += a.x * b0.w;
                acc0[4] += a.x * b1.x; acc0[5] += a.x * b1.y;
                acc0[6] += a.x * b1.z; acc0[7] += a.x * b1.w;
                acc1[0] += a.y * b0.x; acc1[1] += a.y * b0.y;
                acc1[2] += a.y * b0.z; acc1[3] += a.y * b0.w;
                acc1[4] += a.y * b1.x; acc1[5] += a.y * b1.y;
                acc1[6] += a.y * b1.z; acc1[7] += a.y * b1.w;
            }
            // ---- epilogue: dot with Rh[e][ct*64+g*8 .. +7]
            const float* r0p; const float* r1p;
            if (ct < 2) {
                r0p = vnr + (size_t)jL[e0] * 128 + ct * 64 + g * 8;
                r1p = vnr + (size_t)jL[e1] * 128 + ct * 64 + g * 8;
            } else {
                r0p = rel + (size_t)(n0 + e0) * 128 + (ct - 2) * 64 + g * 8;
                r1p = rel + (size_t)(n0 + e1) * 128 + (ct - 2) * 64 + g * 8;
            }
            const float4 ra = *(const float4*)r0p, rb = *(const float4*)(r0p + 4);
            const float4 rc = *(const float4*)r1p, rd = *(const float4*)(r1p + 4);
            float d0 = acc0[0]*ra.x + acc0[1]*ra.y + acc0[2]*ra.z + acc0[3]*ra.w
                     + acc0[4]*rb.x + acc0[5]*rb.y + acc0[6]*rb.z + acc0[7]*rb.w;
            float d1 = acc1[0]*rc.x + acc1[1]*rc.y + acc1[2]*rc.z + acc1[3]*rc.w
                     + acc1[4]*rd.x + acc1[5]*rd.y + acc1[6]*rd.z + acc1[7]*rd.w;
            s0 += (double)d0; s1 += (double)d1;
            if (kt == 0) {   // Rh . bR — count each c exactly once
                const int cb = ct * 64 + g * 8;
                float q0 = ra.x*bRs[cb+0] + ra.y*bRs[cb+1] + ra.z*bRs[cb+2] + ra.w*bRs[cb+3]
                         + rb.x*bRs[cb+4] + rb.y*bRs[cb+5] + rb.z*bRs[cb+6] + rb.w*bRs[cb+7];
                float q1 = rc.x*bRs[cb+0] + rc.y*bRs[cb+1] + rc.z*bRs[cb+2] + rc.w*bRs[cb+3]
                         + rd.x*bRs[cb+4] + rd.y*bRs[cb+5] + rd.z*bRs[cb+6] + rd.w*bRs[cb+7];
                s0 += (double)q0; s1 += (double)q1;
            }
        }
    }
    // reduce over the 8 column-group lanes (xor 1,2,4 stays within the group)
    #pragma unroll
    for (int m = 1; m < 8; m <<= 1) {
        s0 += __shfl_xor(s0, m, 64);
        s1 += __shfl_xor(s1, m, 64);
    }
    if (g == 0) {
        float base = cB[eg];
        logits[n0 + e0] = (float)s0 + base;
        logits[n0 + e1] = (float)s1 + base;
    }
}

// ---------------------------------------------------------------------------
// Kernel 4: deterministic segment max + exp-sum (seg = edges[:,6] is SORTED,
// so each segment is one contiguous run; the run-start thread walks it in
// index order — bitwise deterministic across replays, no atomics).
// ---------------------------------------------------------------------------
__global__ void k_segstats(const int* __restrict__ edges, const float* __restrict__ logits,
                           float* __restrict__ smaxf, float* __restrict__ den)
{
    int n = blockIdx.x * 256 + threadIdx.x;
    if (n >= NN) return;
    int s = edges[(size_t)n * 8 + 6];
    if (n > 0 && edges[(size_t)(n - 1) * 8 + 6] == s) return;   // not a run start
    float m = -INFINITY;
    int k = n;
    while (k < NN && edges[(size_t)k * 8 + 6] == s) {
        m = fmaxf(m, logits[k]);
        ++k;
    }
    float d = 0.f;
    for (int q = n; q < k; ++q) d += expf(logits[q] - m);
    smaxf[s] = m;
    den[s]   = d;
}

// ---------------------------------------------------------------------------
// Kernel 5: per-row target score + full bitonic sort (desc, stable by index)
// + top-64 output write. 64 blocks x 1024 threads.
// ---------------------------------------------------------------------------
__global__ void k_topk(const int* __restrict__ edges, const float* __restrict__ logits,
                       const float* __restrict__ smaxf, const float* __restrict__ den,
                       const float* __restrict__ score, float* __restrict__ out)
{
    __shared__ float vals[1024];
    __shared__ int   idxs[1024];
    const int r = blockIdx.x, t = threadIdx.x;
    const int n = r * 1024 + t;
    {
        int s = edges[(size_t)n * 8 + 6];
        float soft = expf(logits[n] - smaxf[s]) / den[s];
        vals[t] = soft * score[s];
        idxs[t] = t;
    }
    __syncthreads();
    for (int size = 2; size <= 1024; size <<= 1) {
        for (int stride = size >> 1; stride > 0; stride >>= 1) {
            int j = t ^ stride;
            if (j > t) {
                float v1 = vals[t], v2 = vals[j];
                int   i1 = idxs[t], i2 = idxs[j];
                // "v1 comes before v2" in descending stable order
                bool before = (v1 > v2) || (v1 == v2 && i1 < i2);
                bool desc   = ((t & size) == 0);
                if (before != desc) {
                    vals[t] = v2; vals[j] = v1;
                    idxs[t] = i2; idxs[j] = i1;
                }
            }
            __syncthreads();
        }
    }
    if (t < KTOP) {
        int idx  = idxs[t];
        int orig = r * 1024 + idx;
        int s    = edges[(size_t)orig * 8 + 6];
        float soft = expf(logits[orig] - smaxf[s]) / den[s];
        int o = r * KTOP + t;
        out[o]            = vals[t];                 // pruned_target_score
        out[4096 + o]     = soft;                    // pruned_softmax
        #pragma unroll
        for (int q = 0; q < 8; ++q)                  // pruned_edges
            out[8192 + (size_t)o * 8 + q] = (float)edges[(size_t)orig * 8 + q];
        out[40960 + o]    = (float)orig;             // orig_indices
    }
}

// ---------------------------------------------------------------------------
extern "C" void kernel_launch(void* const* d_in, const int* in_sizes, int n_in,
                              void* d_out, int out_size, void* d_ws, size_t ws_size,
                              hipStream_t stream)
{
    (void)in_sizes; (void)n_in; (void)out_size; (void)ws_size;
    const float* score = (const float*)d_in[0];   // visited_node_score (M)
    const float* vnr   = (const float*)d_in[1];   // visited_node_representation (M,128)
    const float* rel   = (const float*)d_in[2];   // rel_emb (N,128)
    const float* qs    = (const float*)d_in[3];   // query_src_ts_emb (B,128)
    const float* qr    = (const float*)d_in[4];   // query_rel_emb (B,128)
    const float* Wq    = (const float*)d_in[5];   // (512,512)
    const float* Wk    = (const float*)d_in[6];   // (512,512)
    const int*   edges = (const int*)  d_in[7];   // (N,8)
    float* out = (float*)d_out;

    float* ws     = (float*)d_ws;
    float* G      = ws;                 // 512*512          = 262144
    float* bL     = G      + 262144;    // 64*256           = 16384
    float* bR     = bL     + 16384;     // 64*256           = 16384
    float* cB     = bR     + 16384;     // 64
    float* smaxf  = cB     + 64;        // 65536
    float* den    = smaxf  + 65536;     // 65536
    float* logits = den    + 65536;     // 65536   (total ~1.9 MB)

    k_gemm_G <<<256, 256, 0, stream>>>(Wq, Wk, G);
    k_batch  <<<64, 256, 0, stream>>>(qs, qr, G, bL, bR, cB);
    k_edge   <<<1024, 256, 0, stream>>>(vnr, rel, edges, G, bL, bR, cB, logits);
    k_segstats<<<256, 256, 0, stream>>>(edges, logits, smaxf, den);
    k_topk   <<<64, 1024, 0, stream>>>(edges, logits, smaxf, den, score, out);
}